// Round 2
// baseline (2061.163 us; speedup 1.0000x reference)
//
#include <hip/hip_runtime.h>

// Problem constants (hardcoded from reference)
#define BD   32768               // boards
#define NPG  54                  // nodes per graph
#define NN   (BD * NPG)          // 1,769,472 nodes
#define NE   (BD * 144)          // 4,718,592 edges
#define DIN  16
#define DH   32
#define DOUT 4
#define GLOBF 16
#define TB   32                  // boards per block in final kernel

// ---------------------------------------------------------------------------
// Scatter 1: aggr1[dst] += x[src] * w   (16-dim rows, 4 threads per edge)
// ---------------------------------------------------------------------------
__global__ __launch_bounds__(256) void k_scatter1(
    const float* __restrict__ x, const int* __restrict__ ei,
    const float* __restrict__ ea, float* __restrict__ aggr1) {
  unsigned t = blockIdx.x * 256u + threadIdx.x;   // NE*4 threads exactly
  unsigned e = t >> 2;
  unsigned p = t & 3u;
  int s = ei[e];
  int d = ei[NE + e];
  float w = ea[e];
  const float4 v = *reinterpret_cast<const float4*>(x + (size_t)s * 16 + p * 4);
  float* dp = aggr1 + (size_t)d * 16 + p * 4;
  unsafeAtomicAdd(dp + 0, v.x * w);
  unsafeAtomicAdd(dp + 1, v.y * w);
  unsafeAtomicAdd(dp + 2, v.z * w);
  unsafeAtomicAdd(dp + 3, v.w * w);
}

// ---------------------------------------------------------------------------
// Node transform: h1 = relu(aggr1@W1_rel + x@W1_root + b1)   [N,32]
// then project:   z2 = h1@W2_rel,  r2 = h1@W2_root + b2       [N,4] each
// (h1 itself is never materialized)
// ---------------------------------------------------------------------------
__global__ __launch_bounds__(256) void k_node(
    const float* __restrict__ x, const float* __restrict__ aggr1,
    const float* __restrict__ W1_rel, const float* __restrict__ b1,
    const float* __restrict__ W1_root,
    const float* __restrict__ W2_rel, const float* __restrict__ b2,
    const float* __restrict__ W2_root,
    float* __restrict__ z2, float* __restrict__ r2) {
  size_t n = (size_t)blockIdx.x * 256 + threadIdx.x;   // NN = 6912*256 exactly
  float a[16], xv[16];
  {
    const float4* ap = reinterpret_cast<const float4*>(aggr1 + n * 16);
    const float4* xp = reinterpret_cast<const float4*>(x + n * 16);
#pragma unroll
    for (int q = 0; q < 4; ++q) {
      float4 t1 = ap[q];
      a[4*q+0] = t1.x; a[4*q+1] = t1.y; a[4*q+2] = t1.z; a[4*q+3] = t1.w;
      float4 t2 = xp[q];
      xv[4*q+0] = t2.x; xv[4*q+1] = t2.y; xv[4*q+2] = t2.z; xv[4*q+3] = t2.w;
    }
  }
  float h[DH];
#pragma unroll
  for (int j = 0; j < DH; ++j) h[j] = b1[j];
#pragma unroll
  for (int i = 0; i < DIN; ++i) {
    float ai = a[i], xi = xv[i];
#pragma unroll
    for (int j = 0; j < DH; ++j)
      h[j] = fmaf(ai, W1_rel[i * DH + j], fmaf(xi, W1_root[i * DH + j], h[j]));
  }
#pragma unroll
  for (int j = 0; j < DH; ++j) h[j] = fmaxf(h[j], 0.f);

  float z[4] = {0.f, 0.f, 0.f, 0.f};
  float r[4] = {b2[0], b2[1], b2[2], b2[3]};
#pragma unroll
  for (int j = 0; j < DH; ++j) {
    float hj = h[j];
#pragma unroll
    for (int k = 0; k < 4; ++k) {
      z[k] = fmaf(hj, W2_rel[j * 4 + k], z[k]);
      r[k] = fmaf(hj, W2_root[j * 4 + k], r[k]);
    }
  }
  *reinterpret_cast<float4*>(z2 + n * 4) = make_float4(z[0], z[1], z[2], z[3]);
  *reinterpret_cast<float4*>(r2 + n * 4) = make_float4(r[0], r[1], r[2], r[3]);
}

// ---------------------------------------------------------------------------
// Scatter 2: aggr2[dst] += z2[src] * w   (4-dim rows, 1 thread per edge)
// ---------------------------------------------------------------------------
__global__ __launch_bounds__(256) void k_scatter2(
    const float* __restrict__ z2, const int* __restrict__ ei,
    const float* __restrict__ ea, float* __restrict__ aggr2) {
  unsigned e = blockIdx.x * 256u + threadIdx.x;   // NE threads exactly
  int s = ei[e];
  int d = ei[NE + e];
  float w = ea[e];
  const float4 v = *reinterpret_cast<const float4*>(z2 + (size_t)s * 4);
  float* dp = aggr2 + (size_t)d * 4;
  unsafeAtomicAdd(dp + 0, v.x * w);
  unsafeAtomicAdd(dp + 1, v.y * w);
  unsafeAtomicAdd(dp + 2, v.z * w);
  unsafeAtomicAdd(dp + 3, v.w * w);
}

// ---------------------------------------------------------------------------
// Final: per-board  embeds = relu(aggr2 + r2) [216],
//        g = MLP(globalFeats) [16],  vec = concat(embeds, g) [232]
//        out = relu(vec@Wo1+bo1) -> relu(@Wo2+bo2) -> @Wo3+bo3  [64]
// TB=32 boards per 256-thread block. GEMMs: A in LDS, W streamed (L2).
// ---------------------------------------------------------------------------
__global__ __launch_bounds__(256) void k_final(
    const float* __restrict__ aggr2, const float* __restrict__ r2,
    const float* __restrict__ gfeat,
    const float* __restrict__ Wg1, const float* __restrict__ bg1,
    const float* __restrict__ Wg2, const float* __restrict__ bg2,
    const float* __restrict__ Wg3, const float* __restrict__ bg3,
    const float* __restrict__ Wo1, const float* __restrict__ bo1,
    const float* __restrict__ Wo2, const float* __restrict__ bo2,
    const float* __restrict__ Wo3, const float* __restrict__ bo3,
    float* __restrict__ out) {
  __shared__ float smem[TB * 232 + TB * 128];   // 46080 B
  float* svec  = smem;             // [TB][232]
  float* sbuf1 = smem + TB * 232;  // [TB][128]
  float* sbuf2 = smem;             // alias svec (dead after layer 1)

  const int tid = threadIdx.x;
  const int b0  = blockIdx.x * TB;

  // stage embeds = relu(aggr2 + r2); r2 already contains b2
  {
    const size_t gbase = (size_t)b0 * 216;
    for (int idx = tid; idx < TB * 216; idx += 256) {
      int b = idx / 216;
      int k = idx - b * 216;
      float v = aggr2[gbase + idx] + r2[gbase + idx];
      svec[b * 232 + k] = fmaxf(v, 0.f);
    }
  }
  // tiny global-feature MLP: 16 -> 8 -> 8 -> 16 (relu each)
  if (tid < TB) {
    const float* gf = gfeat + (size_t)(b0 + tid) * GLOBF;
    float gin[16];
#pragma unroll
    for (int i = 0; i < 16; ++i) gin[i] = gf[i];
    float g1[8];
#pragma unroll
    for (int j = 0; j < 8; ++j) {
      float acc = bg1[j];
#pragma unroll
      for (int i = 0; i < 16; ++i) acc = fmaf(gin[i], Wg1[i * 8 + j], acc);
      g1[j] = fmaxf(acc, 0.f);
    }
    float g2[8];
#pragma unroll
    for (int j = 0; j < 8; ++j) {
      float acc = bg2[j];
#pragma unroll
      for (int i = 0; i < 8; ++i) acc = fmaf(g1[i], Wg2[i * 8 + j], acc);
      g2[j] = fmaxf(acc, 0.f);
    }
#pragma unroll
    for (int j = 0; j < 16; ++j) {
      float acc = bg3[j];
#pragma unroll
      for (int i = 0; i < 8; ++i) acc = fmaf(g2[i], Wg3[i * 16 + j], acc);
      svec[tid * 232 + 216 + j] = fmaxf(acc, 0.f);
    }
  }
  __syncthreads();

  const int c0 = (tid & 31) * 4;   // output column base (0..124)
  const int rb = (tid >> 5) * 4;   // board base within tile (0..28)

  // layer 1: [TB,232] @ [232,128]
  {
    float acc[4][4];
#pragma unroll
    for (int r = 0; r < 4; ++r)
#pragma unroll
      for (int c = 0; c < 4; ++c) acc[r][c] = 0.f;
#pragma unroll 4
    for (int i = 0; i < 232; ++i) {
      const float4 w = *reinterpret_cast<const float4*>(Wo1 + (size_t)i * 128 + c0);
#pragma unroll
      for (int r = 0; r < 4; ++r) {
        float v = svec[(rb + r) * 232 + i];
        acc[r][0] = fmaf(v, w.x, acc[r][0]);
        acc[r][1] = fmaf(v, w.y, acc[r][1]);
        acc[r][2] = fmaf(v, w.z, acc[r][2]);
        acc[r][3] = fmaf(v, w.w, acc[r][3]);
      }
    }
    const float4 bv = *reinterpret_cast<const float4*>(bo1 + c0);
#pragma unroll
    for (int r = 0; r < 4; ++r) {
      float4 o;
      o.x = fmaxf(acc[r][0] + bv.x, 0.f);
      o.y = fmaxf(acc[r][1] + bv.y, 0.f);
      o.z = fmaxf(acc[r][2] + bv.z, 0.f);
      o.w = fmaxf(acc[r][3] + bv.w, 0.f);
      *reinterpret_cast<float4*>(sbuf1 + (rb + r) * 128 + c0) = o;
    }
  }
  __syncthreads();

  // layer 2: [TB,128] @ [128,128]  (writes alias svec; svec reads are done)
  {
    float acc[4][4];
#pragma unroll
    for (int r = 0; r < 4; ++r)
#pragma unroll
      for (int c = 0; c < 4; ++c) acc[r][c] = 0.f;
#pragma unroll 4
    for (int i = 0; i < 128; ++i) {
      const float4 w = *reinterpret_cast<const float4*>(Wo2 + (size_t)i * 128 + c0);
#pragma unroll
      for (int r = 0; r < 4; ++r) {
        float v = sbuf1[(rb + r) * 128 + i];
        acc[r][0] = fmaf(v, w.x, acc[r][0]);
        acc[r][1] = fmaf(v, w.y, acc[r][1]);
        acc[r][2] = fmaf(v, w.z, acc[r][2]);
        acc[r][3] = fmaf(v, w.w, acc[r][3]);
      }
    }
    const float4 bv = *reinterpret_cast<const float4*>(bo2 + c0);
#pragma unroll
    for (int r = 0; r < 4; ++r) {
      float4 o;
      o.x = fmaxf(acc[r][0] + bv.x, 0.f);
      o.y = fmaxf(acc[r][1] + bv.y, 0.f);
      o.z = fmaxf(acc[r][2] + bv.z, 0.f);
      o.w = fmaxf(acc[r][3] + bv.w, 0.f);
      *reinterpret_cast<float4*>(sbuf2 + (rb + r) * 128 + c0) = o;
    }
  }
  __syncthreads();

  // layer 3: [TB,128] @ [128,64] -> global out
  {
    const int c2 = (tid & 31) * 2;   // 0..62
    float acc[4][2];
#pragma unroll
    for (int r = 0; r < 4; ++r) { acc[r][0] = 0.f; acc[r][1] = 0.f; }
#pragma unroll 4
    for (int i = 0; i < 128; ++i) {
      const float2 w = *reinterpret_cast<const float2*>(Wo3 + (size_t)i * 64 + c2);
#pragma unroll
      for (int r = 0; r < 4; ++r) {
        float v = sbuf2[(rb + r) * 128 + i];
        acc[r][0] = fmaf(v, w.x, acc[r][0]);
        acc[r][1] = fmaf(v, w.y, acc[r][1]);
      }
    }
    const float2 bv = *reinterpret_cast<const float2*>(bo3 + c2);
#pragma unroll
    for (int r = 0; r < 4; ++r) {
      float2 o;
      o.x = acc[r][0] + bv.x;
      o.y = acc[r][1] + bv.y;
      *reinterpret_cast<float2*>(out + (size_t)(b0 + rb + r) * 64 + c2) = o;
    }
  }
}

// ---------------------------------------------------------------------------
extern "C" void kernel_launch(void* const* d_in, const int* in_sizes, int n_in,
                              void* d_out, int out_size, void* d_ws, size_t ws_size,
                              hipStream_t stream) {
  const float* x      = (const float*)d_in[0];
  const int*   ei     = (const int*)d_in[1];
  const float* ea     = (const float*)d_in[2];
  const float* gfeat  = (const float*)d_in[3];
  // d_in[4] = isTrain (0 at inference; dropout is identity)
  const float* W1_rel = (const float*)d_in[5];
  const float* b1     = (const float*)d_in[6];
  const float* W1_root= (const float*)d_in[7];
  const float* W2_rel = (const float*)d_in[8];
  const float* b2     = (const float*)d_in[9];
  const float* W2_root= (const float*)d_in[10];
  const float* Wg1 = (const float*)d_in[11];
  const float* bg1 = (const float*)d_in[12];
  const float* Wg2 = (const float*)d_in[13];
  const float* bg2 = (const float*)d_in[14];
  const float* Wg3 = (const float*)d_in[15];
  const float* bg3 = (const float*)d_in[16];
  const float* Wo1 = (const float*)d_in[17];
  const float* bo1 = (const float*)d_in[18];
  const float* Wo2 = (const float*)d_in[19];
  const float* bo2 = (const float*)d_in[20];
  const float* Wo3 = (const float*)d_in[21];
  const float* bo3 = (const float*)d_in[22];
  float* outp = (float*)d_out;

  // workspace layout (peak NN*24*4 = 162 MB)
  float* aggr1 = (float*)d_ws;                  // [NN*16]
  float* z2    = aggr1 + (size_t)NN * 16;       // [NN*4]
  float* r2    = z2 + (size_t)NN * 4;           // [NN*4]
  float* aggr2 = aggr1;                         // reuse (aggr1 dead after k_node)

  hipMemsetAsync(aggr1, 0, (size_t)NN * 16 * sizeof(float), stream);
  k_scatter1<<<(NE * 4) / 256, 256, 0, stream>>>(x, ei, ea, aggr1);
  k_node<<<NN / 256, 256, 0, stream>>>(x, aggr1, W1_rel, b1, W1_root,
                                       W2_rel, b2, W2_root, z2, r2);
  hipMemsetAsync(aggr2, 0, (size_t)NN * 4 * sizeof(float), stream);
  k_scatter2<<<NE / 256, 256, 0, stream>>>(z2, ei, ea, aggr2);
  k_final<<<BD / TB, 256, 0, stream>>>(aggr2, r2, gfeat,
                                       Wg1, bg1, Wg2, bg2, Wg3, bg3,
                                       Wo1, bo1, Wo2, bo2, Wo3, bo3, outp);
}

// Round 3
// 1003.950 us; speedup vs baseline: 2.0531x; 2.0531x over previous
//
#include <hip/hip_runtime.h>

// Problem constants (hardcoded from reference)
#define BD   32768               // boards
#define NPG  54                  // nodes per graph
#define NN   (BD * NPG)          // 1,769,472 nodes
#define NE   (BD * 144)          // 4,718,592 edges
#define DIN  16
#define DH   32
#define GLOBF 16
#define TB   32                  // boards per block in final kernel
#define RB   256                 // nodes per dst bucket (dst>>8)
#define NBK  (NN / RB)           // 6912 buckets
#define STR1 17                  // LDS row stride (floats) conv1 (odd -> bank spread)
#define STR2 5                   // LDS row stride conv2
#define SRCM 0x1FFFFFu           // 21-bit src mask (NN < 2^21)

// ---------------------------------------------------------------------------
// Pass 1: histogram of destination buckets
// ---------------------------------------------------------------------------
__global__ __launch_bounds__(256) void k_hist(const int* __restrict__ ei,
                                              unsigned* __restrict__ hist) {
  unsigned e = blockIdx.x * 256u + threadIdx.x;          // NE threads exactly
  unsigned d = (unsigned)ei[NE + e];
  atomicAdd(&hist[d >> 8], 1u);                          // no-return -> fire&forget
}

// ---------------------------------------------------------------------------
// Pass 2: exclusive scan of 6912 bucket counts (single 1024-thread block)
// ---------------------------------------------------------------------------
__global__ __launch_bounds__(1024) void k_scan(const unsigned* __restrict__ hist,
                                               unsigned* __restrict__ base,
                                               unsigned* __restrict__ cursor) {
  __shared__ unsigned s[1024];
  const int tid = threadIdx.x;
  unsigned loc[7];
  unsigned run = 0;
#pragma unroll
  for (int j = 0; j < 7; ++j) {                          // 1024*7 >= 6912
    int idx = tid * 7 + j;
    unsigned v = (idx < NBK) ? hist[idx] : 0u;
    loc[j] = run; run += v;
  }
  s[tid] = run;
  __syncthreads();
  for (int off = 1; off < 1024; off <<= 1) {             // Hillis-Steele inclusive
    unsigned t = (tid >= off) ? s[tid - off] : 0u;
    __syncthreads();
    s[tid] += t;
    __syncthreads();
  }
  unsigned cb = tid ? s[tid - 1] : 0u;
#pragma unroll
  for (int j = 0; j < 7; ++j) {
    int idx = tid * 7 + j;
    if (idx < NBK) { unsigned b = cb + loc[j]; base[idx] = b; cursor[idx] = b; }
  }
  if (tid == 1023) base[NBK] = s[1023];                  // = NE
}

// ---------------------------------------------------------------------------
// Pass 3: place edge records bucket-sorted: {src | dstLo<<21, w}  (8 B each)
// ---------------------------------------------------------------------------
__global__ __launch_bounds__(256) void k_place(const int* __restrict__ ei,
                                               const float* __restrict__ ea,
                                               unsigned* __restrict__ cursor,
                                               uint2* __restrict__ rec) {
  unsigned e = blockIdx.x * 256u + threadIdx.x;
  unsigned s = (unsigned)ei[e];
  unsigned d = (unsigned)ei[NE + e];
  float w = ea[e];
  unsigned b = d >> 8;
  unsigned pos = atomicAdd(&cursor[b], 1u);
  rec[pos] = make_uint2(s | ((d & 255u) << 21), __float_as_uint(w));
}

// ---------------------------------------------------------------------------
// Conv1 (fused): per dst-bucket, accumulate aggr1 tile in LDS, then apply the
// full node transform: h1 = relu(aggr1@W1_rel + x@W1_root + b1),
// z2 = h1@W2_rel, r2 = h1@W2_root + b2.  aggr1 never hits global memory.
// ---------------------------------------------------------------------------
__global__ __launch_bounds__(256) void k_conv1(
    const uint2* __restrict__ rec, const unsigned* __restrict__ base,
    const float* __restrict__ x,
    const float* __restrict__ W1_rel, const float* __restrict__ b1,
    const float* __restrict__ W1_root,
    const float* __restrict__ W2_rel, const float* __restrict__ b2,
    const float* __restrict__ W2_root,
    float* __restrict__ z2, float* __restrict__ r2) {
  __shared__ float acc[RB * STR1];                       // 17408 B
  const int tid = threadIdx.x;
  const unsigned bk = blockIdx.x;
  for (int i = tid; i < RB * STR1; i += 256) acc[i] = 0.f;
  __syncthreads();

  const unsigned r0 = base[bk], r1 = base[bk + 1];
  const unsigned p = tid & 3u;                           // 4 lanes per record
  for (unsigned i = r0 + (tid >> 2); i < r1; i += 64) {
    uint2 rv = rec[i];
    unsigned src = rv.x & SRCM;
    unsigned lo  = rv.x >> 21;
    float w = __uint_as_float(rv.y);
    const float4 v = *reinterpret_cast<const float4*>(x + (size_t)src * 16 + p * 4);
    float* dp = acc + lo * STR1 + p * 4;
    atomicAdd(dp + 0, v.x * w);
    atomicAdd(dp + 1, v.y * w);
    atomicAdd(dp + 2, v.z * w);
    atomicAdd(dp + 3, v.w * w);
  }
  __syncthreads();

  // fused node transform: node n = bk*RB + tid (one node per thread)
  size_t n = (size_t)bk * RB + tid;
  float a[16], xv[16];
  {
    const float4* xp = reinterpret_cast<const float4*>(x + n * 16);
#pragma unroll
    for (int q = 0; q < 4; ++q) {
      float4 t2 = xp[q];
      xv[4*q+0] = t2.x; xv[4*q+1] = t2.y; xv[4*q+2] = t2.z; xv[4*q+3] = t2.w;
    }
#pragma unroll
    for (int i = 0; i < 16; ++i) a[i] = acc[tid * STR1 + i];
  }
  float h[DH];
#pragma unroll
  for (int j = 0; j < DH; ++j) h[j] = b1[j];
#pragma unroll
  for (int i = 0; i < DIN; ++i) {
    float ai = a[i], xi = xv[i];
#pragma unroll
    for (int j = 0; j < DH; ++j)
      h[j] = fmaf(ai, W1_rel[i * DH + j], fmaf(xi, W1_root[i * DH + j], h[j]));
  }
#pragma unroll
  for (int j = 0; j < DH; ++j) h[j] = fmaxf(h[j], 0.f);

  float z[4] = {0.f, 0.f, 0.f, 0.f};
  float r[4] = {b2[0], b2[1], b2[2], b2[3]};
#pragma unroll
  for (int j = 0; j < DH; ++j) {
    float hj = h[j];
#pragma unroll
    for (int k = 0; k < 4; ++k) {
      z[k] = fmaf(hj, W2_rel[j * 4 + k], z[k]);
      r[k] = fmaf(hj, W2_root[j * 4 + k], r[k]);
    }
  }
  *reinterpret_cast<float4*>(z2 + n * 4) = make_float4(z[0], z[1], z[2], z[3]);
  *reinterpret_cast<float4*>(r2 + n * 4) = make_float4(r[0], r[1], r[2], r[3]);
}

// ---------------------------------------------------------------------------
// Conv2 (fused): per dst-bucket, accumulate aggr2 tile in LDS, then
// embeds = relu(aggr2 + r2).  aggr2 never hits global memory.
// ---------------------------------------------------------------------------
__global__ __launch_bounds__(256) void k_conv2(
    const uint2* __restrict__ rec, const unsigned* __restrict__ base,
    const float* __restrict__ z2, const float* __restrict__ r2,
    float* __restrict__ embeds) {
  __shared__ float acc[RB * STR2];                       // 5120 B
  const int tid = threadIdx.x;
  const unsigned bk = blockIdx.x;
  for (int i = tid; i < RB * STR2; i += 256) acc[i] = 0.f;
  __syncthreads();

  const unsigned r0 = base[bk], r1 = base[bk + 1];
  for (unsigned i = r0 + tid; i < r1; i += 256) {
    uint2 rv = rec[i];
    unsigned src = rv.x & SRCM;
    unsigned lo  = rv.x >> 21;
    float w = __uint_as_float(rv.y);
    const float4 v = *reinterpret_cast<const float4*>(z2 + (size_t)src * 4);
    float* dp = acc + lo * STR2;
    atomicAdd(dp + 0, v.x * w);
    atomicAdd(dp + 1, v.y * w);
    atomicAdd(dp + 2, v.z * w);
    atomicAdd(dp + 3, v.w * w);
  }
  __syncthreads();

  size_t n = (size_t)bk * RB + tid;
  const float4 rr = *reinterpret_cast<const float4*>(r2 + n * 4);
  float4 o;
  o.x = fmaxf(acc[tid * STR2 + 0] + rr.x, 0.f);
  o.y = fmaxf(acc[tid * STR2 + 1] + rr.y, 0.f);
  o.z = fmaxf(acc[tid * STR2 + 2] + rr.z, 0.f);
  o.w = fmaxf(acc[tid * STR2 + 3] + rr.w, 0.f);
  *reinterpret_cast<float4*>(embeds + n * 4) = o;
}

// ---------------------------------------------------------------------------
// Final: per-board  vec = concat(embeds[b,216], gMLP(globalFeats[b]))  [232]
//        out = relu(vec@Wo1+bo1) -> relu(@Wo2+bo2) -> @Wo3+bo3  [64]
// ---------------------------------------------------------------------------
__global__ __launch_bounds__(256) void k_final(
    const float* __restrict__ embeds, const float* __restrict__ gfeat,
    const float* __restrict__ Wg1, const float* __restrict__ bg1,
    const float* __restrict__ Wg2, const float* __restrict__ bg2,
    const float* __restrict__ Wg3, const float* __restrict__ bg3,
    const float* __restrict__ Wo1, const float* __restrict__ bo1,
    const float* __restrict__ Wo2, const float* __restrict__ bo2,
    const float* __restrict__ Wo3, const float* __restrict__ bo3,
    float* __restrict__ out) {
  __shared__ float smem[TB * 232 + TB * 128];   // 46080 B
  float* svec  = smem;             // [TB][232]
  float* sbuf1 = smem + TB * 232;  // [TB][128]
  float* sbuf2 = smem;             // alias svec (dead after layer 1)

  const int tid = threadIdx.x;
  const int b0  = blockIdx.x * TB;

  // stage embeds (already relu'd)
  {
    const size_t gbase = (size_t)b0 * 216;
    for (int idx = tid; idx < TB * 216; idx += 256) {
      int b = idx / 216;
      int k = idx - b * 216;
      svec[b * 232 + k] = embeds[gbase + idx];
    }
  }
  // tiny global-feature MLP: 16 -> 8 -> 8 -> 16 (relu each)
  if (tid < TB) {
    const float* gf = gfeat + (size_t)(b0 + tid) * GLOBF;
    float gin[16];
#pragma unroll
    for (int i = 0; i < 16; ++i) gin[i] = gf[i];
    float g1[8];
#pragma unroll
    for (int j = 0; j < 8; ++j) {
      float acc = bg1[j];
#pragma unroll
      for (int i = 0; i < 16; ++i) acc = fmaf(gin[i], Wg1[i * 8 + j], acc);
      g1[j] = fmaxf(acc, 0.f);
    }
    float g2[8];
#pragma unroll
    for (int j = 0; j < 8; ++j) {
      float acc = bg2[j];
#pragma unroll
      for (int i = 0; i < 8; ++i) acc = fmaf(g1[i], Wg2[i * 8 + j], acc);
      g2[j] = fmaxf(acc, 0.f);
    }
#pragma unroll
    for (int j = 0; j < 16; ++j) {
      float acc = bg3[j];
#pragma unroll
      for (int i = 0; i < 8; ++i) acc = fmaf(g2[i], Wg3[i * 16 + j], acc);
      svec[tid * 232 + 216 + j] = fmaxf(acc, 0.f);
    }
  }
  __syncthreads();

  const int c0 = (tid & 31) * 4;   // output column base (0..124)
  const int rb = (tid >> 5) * 4;   // board base within tile (0..28)

  // layer 1: [TB,232] @ [232,128]
  {
    float acc[4][4];
#pragma unroll
    for (int r = 0; r < 4; ++r)
#pragma unroll
      for (int c = 0; c < 4; ++c) acc[r][c] = 0.f;
#pragma unroll 4
    for (int i = 0; i < 232; ++i) {
      const float4 w = *reinterpret_cast<const float4*>(Wo1 + (size_t)i * 128 + c0);
#pragma unroll
      for (int r = 0; r < 4; ++r) {
        float v = svec[(rb + r) * 232 + i];
        acc[r][0] = fmaf(v, w.x, acc[r][0]);
        acc[r][1] = fmaf(v, w.y, acc[r][1]);
        acc[r][2] = fmaf(v, w.z, acc[r][2]);
        acc[r][3] = fmaf(v, w.w, acc[r][3]);
      }
    }
    const float4 bv = *reinterpret_cast<const float4*>(bo1 + c0);
#pragma unroll
    for (int r = 0; r < 4; ++r) {
      float4 o;
      o.x = fmaxf(acc[r][0] + bv.x, 0.f);
      o.y = fmaxf(acc[r][1] + bv.y, 0.f);
      o.z = fmaxf(acc[r][2] + bv.z, 0.f);
      o.w = fmaxf(acc[r][3] + bv.w, 0.f);
      *reinterpret_cast<float4*>(sbuf1 + (rb + r) * 128 + c0) = o;
    }
  }
  __syncthreads();

  // layer 2: [TB,128] @ [128,128]
  {
    float acc[4][4];
#pragma unroll
    for (int r = 0; r < 4; ++r)
#pragma unroll
      for (int c = 0; c < 4; ++c) acc[r][c] = 0.f;
#pragma unroll 4
    for (int i = 0; i < 128; ++i) {
      const float4 w = *reinterpret_cast<const float4*>(Wo2 + (size_t)i * 128 + c0);
#pragma unroll
      for (int r = 0; r < 4; ++r) {
        float v = sbuf1[(rb + r) * 128 + i];
        acc[r][0] = fmaf(v, w.x, acc[r][0]);
        acc[r][1] = fmaf(v, w.y, acc[r][1]);
        acc[r][2] = fmaf(v, w.z, acc[r][2]);
        acc[r][3] = fmaf(v, w.w, acc[r][3]);
      }
    }
    const float4 bv = *reinterpret_cast<const float4*>(bo2 + c0);
#pragma unroll
    for (int r = 0; r < 4; ++r) {
      float4 o;
      o.x = fmaxf(acc[r][0] + bv.x, 0.f);
      o.y = fmaxf(acc[r][1] + bv.y, 0.f);
      o.z = fmaxf(acc[r][2] + bv.z, 0.f);
      o.w = fmaxf(acc[r][3] + bv.w, 0.f);
      *reinterpret_cast<float4*>(sbuf2 + (rb + r) * 128 + c0) = o;
    }
  }
  __syncthreads();

  // layer 3: [TB,128] @ [128,64] -> global out
  {
    const int c2 = (tid & 31) * 2;   // 0..62
    float acc[4][2];
#pragma unroll
    for (int r = 0; r < 4; ++r) { acc[r][0] = 0.f; acc[r][1] = 0.f; }
#pragma unroll 4
    for (int i = 0; i < 128; ++i) {
      const float2 w = *reinterpret_cast<const float2*>(Wo3 + (size_t)i * 64 + c2);
#pragma unroll
      for (int r = 0; r < 4; ++r) {
        float v = sbuf2[(rb + r) * 128 + i];
        acc[r][0] = fmaf(v, w.x, acc[r][0]);
        acc[r][1] = fmaf(v, w.y, acc[r][1]);
      }
    }
    const float2 bv = *reinterpret_cast<const float2*>(bo3 + c2);
#pragma unroll
    for (int r = 0; r < 4; ++r) {
      float2 o;
      o.x = acc[r][0] + bv.x;
      o.y = acc[r][1] + bv.y;
      *reinterpret_cast<float2*>(out + (size_t)(b0 + rb + r) * 64 + c2) = o;
    }
  }
}

// ---------------------------------------------------------------------------
extern "C" void kernel_launch(void* const* d_in, const int* in_sizes, int n_in,
                              void* d_out, int out_size, void* d_ws, size_t ws_size,
                              hipStream_t stream) {
  const float* x      = (const float*)d_in[0];
  const int*   ei     = (const int*)d_in[1];
  const float* ea     = (const float*)d_in[2];
  const float* gfeat  = (const float*)d_in[3];
  // d_in[4] = isTrain (0 at inference; dropout is identity)
  const float* W1_rel = (const float*)d_in[5];
  const float* b1     = (const float*)d_in[6];
  const float* W1_root= (const float*)d_in[7];
  const float* W2_rel = (const float*)d_in[8];
  const float* b2     = (const float*)d_in[9];
  const float* W2_root= (const float*)d_in[10];
  const float* Wg1 = (const float*)d_in[11];
  const float* bg1 = (const float*)d_in[12];
  const float* Wg2 = (const float*)d_in[13];
  const float* bg2 = (const float*)d_in[14];
  const float* Wg3 = (const float*)d_in[15];
  const float* bg3 = (const float*)d_in[16];
  const float* Wo1 = (const float*)d_in[17];
  const float* bo1 = (const float*)d_in[18];
  const float* Wo2 = (const float*)d_in[19];
  const float* bo2 = (const float*)d_in[20];
  const float* Wo3 = (const float*)d_in[21];
  const float* bo3 = (const float*)d_in[22];
  float* outp = (float*)d_out;

  // workspace layout (~123 MB total; previous kernel used 162 MB)
  uint2*    rec    = (uint2*)d_ws;                       // NE * 8 B
  float*    z2     = (float*)(rec + NE);                 // NN*4 f
  float*    r2     = z2 + (size_t)NN * 4;                // NN*4 f
  float*    embeds = r2 + (size_t)NN * 4;                // NN*4 f
  unsigned* hist   = (unsigned*)(embeds + (size_t)NN * 4); // NBK
  unsigned* base   = hist + NBK;                         // NBK+1
  unsigned* cursor = base + NBK + 1;                     // NBK

  hipMemsetAsync(hist, 0, NBK * sizeof(unsigned), stream);
  k_hist <<<NE / 256, 256, 0, stream>>>(ei, hist);
  k_scan <<<1, 1024, 0, stream>>>(hist, base, cursor);
  k_place<<<NE / 256, 256, 0, stream>>>(ei, ea, cursor, rec);
  k_conv1<<<NBK, 256, 0, stream>>>(rec, base, x, W1_rel, b1, W1_root,
                                   W2_rel, b2, W2_root, z2, r2);
  k_conv2<<<NBK, 256, 0, stream>>>(rec, base, z2, r2, embeds);
  k_final<<<BD / TB, 256, 0, stream>>>(embeds, gfeat,
                                       Wg1, bg1, Wg2, bg2, Wg3, bg3,
                                       Wo1, bo1, Wo2, bo2, Wo3, bo3, outp);
}

// Round 4
// 999.416 us; speedup vs baseline: 2.0624x; 1.0045x over previous
//
#include <hip/hip_runtime.h>

// Problem constants (hardcoded from reference)
#define BD   32768               // boards
#define NPG  54                  // nodes per graph
#define NN   (BD * NPG)          // 1,769,472 nodes
#define NE   (BD * 144)          // 4,718,592 edges
#define DIN  16
#define DH   32
#define GLOBF 16
#define TB   32                  // boards per block in final kernel
#define RB   256                 // nodes per dst bucket (dst>>8)
#define NBK  (NN / RB)           // 6912 buckets
#define STR1 17                  // LDS row stride (floats) conv1 (odd -> bank spread)
#define STR2 5                   // LDS row stride conv2
#define SRCM 0x1FFFFFu           // 21-bit src mask (NN < 2^21)

// ---------------------------------------------------------------------------
// Pass 1: histogram of destination buckets
// ---------------------------------------------------------------------------
__global__ __launch_bounds__(256) void k_hist(const int* __restrict__ ei,
                                              unsigned* __restrict__ hist) {
  unsigned e = blockIdx.x * 256u + threadIdx.x;          // NE threads exactly
  unsigned d = (unsigned)ei[NE + e];
  atomicAdd(&hist[d >> 8], 1u);                          // no-return -> fire&forget
}

// ---------------------------------------------------------------------------
// Pass 2: exclusive scan of 6912 bucket counts (single 1024-thread block)
// ---------------------------------------------------------------------------
__global__ __launch_bounds__(1024) void k_scan(const unsigned* __restrict__ hist,
                                               unsigned* __restrict__ base,
                                               unsigned* __restrict__ cursor) {
  __shared__ unsigned s[1024];
  const int tid = threadIdx.x;
  unsigned loc[7];
  unsigned run = 0;
#pragma unroll
  for (int j = 0; j < 7; ++j) {                          // 1024*7 >= 6912
    int idx = tid * 7 + j;
    unsigned v = (idx < NBK) ? hist[idx] : 0u;
    loc[j] = run; run += v;
  }
  s[tid] = run;
  __syncthreads();
  for (int off = 1; off < 1024; off <<= 1) {             // Hillis-Steele inclusive
    unsigned t = (tid >= off) ? s[tid - off] : 0u;
    __syncthreads();
    s[tid] += t;
    __syncthreads();
  }
  unsigned cb = tid ? s[tid - 1] : 0u;
#pragma unroll
  for (int j = 0; j < 7; ++j) {
    int idx = tid * 7 + j;
    if (idx < NBK) { unsigned b = cb + loc[j]; base[idx] = b; cursor[idx] = b; }
  }
  if (tid == 1023) base[NBK] = s[1023];                  // = NE
}

// ---------------------------------------------------------------------------
// Pass 3: place edge records bucket-sorted: {src | dstLo<<21, w}  (8 B each)
// ---------------------------------------------------------------------------
__global__ __launch_bounds__(256) void k_place(const int* __restrict__ ei,
                                               const float* __restrict__ ea,
                                               unsigned* __restrict__ cursor,
                                               uint2* __restrict__ rec) {
  unsigned e = blockIdx.x * 256u + threadIdx.x;
  unsigned s = (unsigned)ei[e];
  unsigned d = (unsigned)ei[NE + e];
  float w = ea[e];
  unsigned b = d >> 8;
  unsigned pos = atomicAdd(&cursor[b], 1u);
  rec[pos] = make_uint2(s | ((d & 255u) << 21), __float_as_uint(w));
}

// ---------------------------------------------------------------------------
// Conv1 (fused): per dst-bucket, accumulate aggr1 tile in LDS (4-deep
// software pipeline for gather MLP), then apply the full node transform:
// h1 = relu(aggr1@W1_rel + x@W1_root + b1), z2 = h1@W2_rel, r2 = h1@W2_root+b2
// ---------------------------------------------------------------------------
__global__ __launch_bounds__(256) void k_conv1(
    const uint2* __restrict__ rec, const unsigned* __restrict__ base,
    const float* __restrict__ x,
    const float* __restrict__ W1_rel, const float* __restrict__ b1,
    const float* __restrict__ W1_root,
    const float* __restrict__ W2_rel, const float* __restrict__ b2,
    const float* __restrict__ W2_root,
    float* __restrict__ z2, float* __restrict__ r2) {
  __shared__ float acc[RB * STR1];                       // 17408 B
  const int tid = threadIdx.x;
  const unsigned bk = blockIdx.x;
  for (int i = tid; i < RB * STR1; i += 256) acc[i] = 0.f;
  __syncthreads();

  const unsigned r0 = base[bk], r1 = base[bk + 1];
  const unsigned cnt = r1 - r0;
  const unsigned p4 = (tid & 3u) * 4;                    // this lane's 16B slice
  const unsigned g  = tid >> 2;                          // lane-group 0..63

  // main: chunks of 256 records; lane-group g owns records g*4..g*4+3 (contiguous)
  const unsigned nch = cnt >> 8;
  for (unsigned c = 0; c < nch; ++c) {
    const unsigned ib = r0 + c * 256u + g * 4u;
    uint2 ra = rec[ib + 0];
    uint2 rb = rec[ib + 1];
    uint2 rc = rec[ib + 2];
    uint2 rd = rec[ib + 3];
    const float4 va = *reinterpret_cast<const float4*>(x + (size_t)(ra.x & SRCM) * 16 + p4);
    const float4 vb = *reinterpret_cast<const float4*>(x + (size_t)(rb.x & SRCM) * 16 + p4);
    const float4 vc = *reinterpret_cast<const float4*>(x + (size_t)(rc.x & SRCM) * 16 + p4);
    const float4 vd = *reinterpret_cast<const float4*>(x + (size_t)(rd.x & SRCM) * 16 + p4);
    {
      float w = __uint_as_float(ra.y); float* dp = acc + (ra.x >> 21) * STR1 + p4;
      atomicAdd(dp + 0, va.x * w); atomicAdd(dp + 1, va.y * w);
      atomicAdd(dp + 2, va.z * w); atomicAdd(dp + 3, va.w * w);
    }
    {
      float w = __uint_as_float(rb.y); float* dp = acc + (rb.x >> 21) * STR1 + p4;
      atomicAdd(dp + 0, vb.x * w); atomicAdd(dp + 1, vb.y * w);
      atomicAdd(dp + 2, vb.z * w); atomicAdd(dp + 3, vb.w * w);
    }
    {
      float w = __uint_as_float(rc.y); float* dp = acc + (rc.x >> 21) * STR1 + p4;
      atomicAdd(dp + 0, vc.x * w); atomicAdd(dp + 1, vc.y * w);
      atomicAdd(dp + 2, vc.z * w); atomicAdd(dp + 3, vc.w * w);
    }
    {
      float w = __uint_as_float(rd.y); float* dp = acc + (rd.x >> 21) * STR1 + p4;
      atomicAdd(dp + 0, vd.x * w); atomicAdd(dp + 1, vd.y * w);
      atomicAdd(dp + 2, vd.z * w); atomicAdd(dp + 3, vd.w * w);
    }
  }
  // tail: up to 255 records, stride-64 single
  for (unsigned i = r0 + nch * 256u + g; i < r1; i += 64) {
    uint2 rv = rec[i];
    float w = __uint_as_float(rv.y);
    const float4 v = *reinterpret_cast<const float4*>(x + (size_t)(rv.x & SRCM) * 16 + p4);
    float* dp = acc + (rv.x >> 21) * STR1 + p4;
    atomicAdd(dp + 0, v.x * w); atomicAdd(dp + 1, v.y * w);
    atomicAdd(dp + 2, v.z * w); atomicAdd(dp + 3, v.w * w);
  }
  __syncthreads();

  // fused node transform: node n = bk*RB + tid (one node per thread)
  size_t n = (size_t)bk * RB + tid;
  float a[16], xv[16];
  {
    const float4* xp = reinterpret_cast<const float4*>(x + n * 16);
#pragma unroll
    for (int q = 0; q < 4; ++q) {
      float4 t2 = xp[q];
      xv[4*q+0] = t2.x; xv[4*q+1] = t2.y; xv[4*q+2] = t2.z; xv[4*q+3] = t2.w;
    }
#pragma unroll
    for (int i = 0; i < 16; ++i) a[i] = acc[tid * STR1 + i];
  }
  float h[DH];
#pragma unroll
  for (int j = 0; j < DH; ++j) h[j] = b1[j];
#pragma unroll
  for (int i = 0; i < DIN; ++i) {
    float ai = a[i], xi = xv[i];
#pragma unroll
    for (int j = 0; j < DH; ++j)
      h[j] = fmaf(ai, W1_rel[i * DH + j], fmaf(xi, W1_root[i * DH + j], h[j]));
  }
#pragma unroll
  for (int j = 0; j < DH; ++j) h[j] = fmaxf(h[j], 0.f);

  float z[4] = {0.f, 0.f, 0.f, 0.f};
  float r[4] = {b2[0], b2[1], b2[2], b2[3]};
#pragma unroll
  for (int j = 0; j < DH; ++j) {
    float hj = h[j];
#pragma unroll
    for (int k = 0; k < 4; ++k) {
      z[k] = fmaf(hj, W2_rel[j * 4 + k], z[k]);
      r[k] = fmaf(hj, W2_root[j * 4 + k], r[k]);
    }
  }
  *reinterpret_cast<float4*>(z2 + n * 4) = make_float4(z[0], z[1], z[2], z[3]);
  *reinterpret_cast<float4*>(r2 + n * 4) = make_float4(r[0], r[1], r[2], r[3]);
}

// ---------------------------------------------------------------------------
// Conv2 (fused): per dst-bucket, accumulate aggr2 tile in LDS (4 lanes per
// record, 4-deep pipeline), then embeds = relu(aggr2 + r2).
// ---------------------------------------------------------------------------
__global__ __launch_bounds__(256) void k_conv2(
    const uint2* __restrict__ rec, const unsigned* __restrict__ base,
    const float* __restrict__ z2, const float* __restrict__ r2,
    float* __restrict__ embeds) {
  __shared__ float acc[RB * STR2];                       // 5120 B
  const int tid = threadIdx.x;
  const unsigned bk = blockIdx.x;
  for (int i = tid; i < RB * STR2; i += 256) acc[i] = 0.f;
  __syncthreads();

  const unsigned r0 = base[bk], r1 = base[bk + 1];
  const unsigned cnt = r1 - r0;
  const unsigned p = tid & 3u;                           // this lane's dword
  const unsigned g = tid >> 2;

  const unsigned nch = cnt >> 8;
  for (unsigned c = 0; c < nch; ++c) {
    const unsigned ib = r0 + c * 256u + g * 4u;
    uint2 ra = rec[ib + 0];
    uint2 rb = rec[ib + 1];
    uint2 rc = rec[ib + 2];
    uint2 rd = rec[ib + 3];
    float va = z2[(size_t)(ra.x & SRCM) * 4 + p];
    float vb = z2[(size_t)(rb.x & SRCM) * 4 + p];
    float vc = z2[(size_t)(rc.x & SRCM) * 4 + p];
    float vd = z2[(size_t)(rd.x & SRCM) * 4 + p];
    atomicAdd(&acc[(ra.x >> 21) * STR2 + p], va * __uint_as_float(ra.y));
    atomicAdd(&acc[(rb.x >> 21) * STR2 + p], vb * __uint_as_float(rb.y));
    atomicAdd(&acc[(rc.x >> 21) * STR2 + p], vc * __uint_as_float(rc.y));
    atomicAdd(&acc[(rd.x >> 21) * STR2 + p], vd * __uint_as_float(rd.y));
  }
  for (unsigned i = r0 + nch * 256u + g; i < r1; i += 64) {
    uint2 rv = rec[i];
    float v = z2[(size_t)(rv.x & SRCM) * 4 + p];
    atomicAdd(&acc[(rv.x >> 21) * STR2 + p], v * __uint_as_float(rv.y));
  }
  __syncthreads();

  size_t n = (size_t)bk * RB + tid;
  const float4 rr = *reinterpret_cast<const float4*>(r2 + n * 4);
  float4 o;
  o.x = fmaxf(acc[tid * STR2 + 0] + rr.x, 0.f);
  o.y = fmaxf(acc[tid * STR2 + 1] + rr.y, 0.f);
  o.z = fmaxf(acc[tid * STR2 + 2] + rr.z, 0.f);
  o.w = fmaxf(acc[tid * STR2 + 3] + rr.w, 0.f);
  *reinterpret_cast<float4*>(embeds + n * 4) = o;
}

// ---------------------------------------------------------------------------
// Final: per-board  vec = concat(embeds[b,216], gMLP(globalFeats[b]))  [232]
//        out = relu(vec@Wo1+bo1) -> relu(@Wo2+bo2) -> @Wo3+bo3  [64]
// ---------------------------------------------------------------------------
__global__ __launch_bounds__(256) void k_final(
    const float* __restrict__ embeds, const float* __restrict__ gfeat,
    const float* __restrict__ Wg1, const float* __restrict__ bg1,
    const float* __restrict__ Wg2, const float* __restrict__ bg2,
    const float* __restrict__ Wg3, const float* __restrict__ bg3,
    const float* __restrict__ Wo1, const float* __restrict__ bo1,
    const float* __restrict__ Wo2, const float* __restrict__ bo2,
    const float* __restrict__ Wo3, const float* __restrict__ bo3,
    float* __restrict__ out) {
  __shared__ float smem[TB * 232 + TB * 128];   // 46080 B
  float* svec  = smem;             // [TB][232]
  float* sbuf1 = smem + TB * 232;  // [TB][128]
  float* sbuf2 = smem;             // alias svec (dead after layer 1)

  const int tid = threadIdx.x;
  const int b0  = blockIdx.x * TB;

  // stage embeds (already relu'd)
  {
    const size_t gbase = (size_t)b0 * 216;
    for (int idx = tid; idx < TB * 216; idx += 256) {
      int b = idx / 216;
      int k = idx - b * 216;
      svec[b * 232 + k] = embeds[gbase + idx];
    }
  }
  // tiny global-feature MLP: 16 -> 8 -> 8 -> 16 (relu each)
  if (tid < TB) {
    const float* gf = gfeat + (size_t)(b0 + tid) * GLOBF;
    float gin[16];
#pragma unroll
    for (int i = 0; i < 16; ++i) gin[i] = gf[i];
    float g1[8];
#pragma unroll
    for (int j = 0; j < 8; ++j) {
      float acc = bg1[j];
#pragma unroll
      for (int i = 0; i < 16; ++i) acc = fmaf(gin[i], Wg1[i * 8 + j], acc);
      g1[j] = fmaxf(acc, 0.f);
    }
    float g2[8];
#pragma unroll
    for (int j = 0; j < 8; ++j) {
      float acc = bg2[j];
#pragma unroll
      for (int i = 0; i < 8; ++i) acc = fmaf(g1[i], Wg2[i * 8 + j], acc);
      g2[j] = fmaxf(acc, 0.f);
    }
#pragma unroll
    for (int j = 0; j < 16; ++j) {
      float acc = bg3[j];
#pragma unroll
      for (int i = 0; i < 8; ++i) acc = fmaf(g2[i], Wg3[i * 16 + j], acc);
      svec[tid * 232 + 216 + j] = fmaxf(acc, 0.f);
    }
  }
  __syncthreads();

  const int c0 = (tid & 31) * 4;   // output column base (0..124)
  const int rb = (tid >> 5) * 4;   // board base within tile (0..28)

  // layer 1: [TB,232] @ [232,128]
  {
    float acc[4][4];
#pragma unroll
    for (int r = 0; r < 4; ++r)
#pragma unroll
      for (int c = 0; c < 4; ++c) acc[r][c] = 0.f;
#pragma unroll 4
    for (int i = 0; i < 232; ++i) {
      const float4 w = *reinterpret_cast<const float4*>(Wo1 + (size_t)i * 128 + c0);
#pragma unroll
      for (int r = 0; r < 4; ++r) {
        float v = svec[(rb + r) * 232 + i];
        acc[r][0] = fmaf(v, w.x, acc[r][0]);
        acc[r][1] = fmaf(v, w.y, acc[r][1]);
        acc[r][2] = fmaf(v, w.z, acc[r][2]);
        acc[r][3] = fmaf(v, w.w, acc[r][3]);
      }
    }
    const float4 bv = *reinterpret_cast<const float4*>(bo1 + c0);
#pragma unroll
    for (int r = 0; r < 4; ++r) {
      float4 o;
      o.x = fmaxf(acc[r][0] + bv.x, 0.f);
      o.y = fmaxf(acc[r][1] + bv.y, 0.f);
      o.z = fmaxf(acc[r][2] + bv.z, 0.f);
      o.w = fmaxf(acc[r][3] + bv.w, 0.f);
      *reinterpret_cast<float4*>(sbuf1 + (rb + r) * 128 + c0) = o;
    }
  }
  __syncthreads();

  // layer 2: [TB,128] @ [128,128]
  {
    float acc[4][4];
#pragma unroll
    for (int r = 0; r < 4; ++r)
#pragma unroll
      for (int c = 0; c < 4; ++c) acc[r][c] = 0.f;
#pragma unroll 4
    for (int i = 0; i < 128; ++i) {
      const float4 w = *reinterpret_cast<const float4*>(Wo2 + (size_t)i * 128 + c0);
#pragma unroll
      for (int r = 0; r < 4; ++r) {
        float v = sbuf1[(rb + r) * 128 + i];
        acc[r][0] = fmaf(v, w.x, acc[r][0]);
        acc[r][1] = fmaf(v, w.y, acc[r][1]);
        acc[r][2] = fmaf(v, w.z, acc[r][2]);
        acc[r][3] = fmaf(v, w.w, acc[r][3]);
      }
    }
    const float4 bv = *reinterpret_cast<const float4*>(bo2 + c0);
#pragma unroll
    for (int r = 0; r < 4; ++r) {
      float4 o;
      o.x = fmaxf(acc[r][0] + bv.x, 0.f);
      o.y = fmaxf(acc[r][1] + bv.y, 0.f);
      o.z = fmaxf(acc[r][2] + bv.z, 0.f);
      o.w = fmaxf(acc[r][3] + bv.w, 0.f);
      *reinterpret_cast<float4*>(sbuf2 + (rb + r) * 128 + c0) = o;
    }
  }
  __syncthreads();

  // layer 3: [TB,128] @ [128,64] -> global out
  {
    const int c2 = (tid & 31) * 2;   // 0..62
    float acc[4][2];
#pragma unroll
    for (int r = 0; r < 4; ++r) { acc[r][0] = 0.f; acc[r][1] = 0.f; }
#pragma unroll 4
    for (int i = 0; i < 128; ++i) {
      const float2 w = *reinterpret_cast<const float2*>(Wo3 + (size_t)i * 64 + c2);
#pragma unroll
      for (int r = 0; r < 4; ++r) {
        float v = sbuf2[(rb + r) * 128 + i];
        acc[r][0] = fmaf(v, w.x, acc[r][0]);
        acc[r][1] = fmaf(v, w.y, acc[r][1]);
      }
    }
    const float2 bv = *reinterpret_cast<const float2*>(bo3 + c2);
#pragma unroll
    for (int r = 0; r < 4; ++r) {
      float2 o;
      o.x = acc[r][0] + bv.x;
      o.y = acc[r][1] + bv.y;
      *reinterpret_cast<float2*>(out + (size_t)(b0 + rb + r) * 64 + c2) = o;
    }
  }
}

// ---------------------------------------------------------------------------
extern "C" void kernel_launch(void* const* d_in, const int* in_sizes, int n_in,
                              void* d_out, int out_size, void* d_ws, size_t ws_size,
                              hipStream_t stream) {
  const float* x      = (const float*)d_in[0];
  const int*   ei     = (const int*)d_in[1];
  const float* ea     = (const float*)d_in[2];
  const float* gfeat  = (const float*)d_in[3];
  // d_in[4] = isTrain (0 at inference; dropout is identity)
  const float* W1_rel = (const float*)d_in[5];
  const float* b1     = (const float*)d_in[6];
  const float* W1_root= (const float*)d_in[7];
  const float* W2_rel = (const float*)d_in[8];
  const float* b2     = (const float*)d_in[9];
  const float* W2_root= (const float*)d_in[10];
  const float* Wg1 = (const float*)d_in[11];
  const float* bg1 = (const float*)d_in[12];
  const float* Wg2 = (const float*)d_in[13];
  const float* bg2 = (const float*)d_in[14];
  const float* Wg3 = (const float*)d_in[15];
  const float* bg3 = (const float*)d_in[16];
  const float* Wo1 = (const float*)d_in[17];
  const float* bo1 = (const float*)d_in[18];
  const float* Wo2 = (const float*)d_in[19];
  const float* bo2 = (const float*)d_in[20];
  const float* Wo3 = (const float*)d_in[21];
  const float* bo3 = (const float*)d_in[22];
  float* outp = (float*)d_out;

  // workspace layout (~123 MB total)
  uint2*    rec    = (uint2*)d_ws;                       // NE * 8 B
  float*    z2     = (float*)(rec + NE);                 // NN*4 f
  float*    r2     = z2 + (size_t)NN * 4;                // NN*4 f
  float*    embeds = r2 + (size_t)NN * 4;                // NN*4 f
  unsigned* hist   = (unsigned*)(embeds + (size_t)NN * 4); // NBK
  unsigned* base   = hist + NBK;                         // NBK+1
  unsigned* cursor = base + NBK + 1;                     // NBK

  hipMemsetAsync(hist, 0, NBK * sizeof(unsigned), stream);
  k_hist <<<NE / 256, 256, 0, stream>>>(ei, hist);
  k_scan <<<1, 1024, 0, stream>>>(hist, base, cursor);
  k_place<<<NE / 256, 256, 0, stream>>>(ei, ea, cursor, rec);
  k_conv1<<<NBK, 256, 0, stream>>>(rec, base, x, W1_rel, b1, W1_root,
                                   W2_rel, b2, W2_root, z2, r2);
  k_conv2<<<NBK, 256, 0, stream>>>(rec, base, z2, r2, embeds);
  k_final<<<BD / TB, 256, 0, stream>>>(embeds, gfeat,
                                       Wg1, bg1, Wg2, bg2, Wg3, bg3,
                                       Wo1, bo1, Wo2, bo2, Wo3, bo3, outp);
}